// Round 14
// baseline (257.216 us; speedup 1.0000x reference)
//
#include <hip/hip_runtime.h>

// Problem constants
#define Hn  16
#define Dh  64
#define Bb  4
#define Tn  2048
#define En  1024
#define Mn  8192           // B*T
#define N1  3072           // 3*E
#define Kn  1024           // E

typedef __attribute__((ext_vector_type(8)))  short  short8;
typedef __attribute__((ext_vector_type(4)))  short  short4v;
typedef __attribute__((ext_vector_type(4)))  float  f32x4;
typedef __attribute__((ext_vector_type(16))) float  f32x16;
typedef __attribute__((ext_vector_type(8)))  __bf16 bf16x8;
typedef __attribute__((ext_vector_type(4)))  int    i32x4;
typedef __attribute__((ext_vector_type(2)))  int    i32x2;

__device__ __forceinline__ float b2f(short s) {
  unsigned u = ((unsigned)(unsigned short)s) << 16;
  return __builtin_bit_cast(float, u);
}
__device__ __forceinline__ short f2b(float f) {
  unsigned u = __builtin_bit_cast(unsigned, f);
  u += 0x7fffu + ((u >> 16) & 1u);
  return (short)(u >> 16);
}
__device__ __forceinline__ f32x4 mfma16(short8 a, short8 b, f32x4 c) {
  return __builtin_amdgcn_mfma_f32_16x16x32_bf16(
      __builtin_bit_cast(bf16x8, a), __builtin_bit_cast(bf16x8, b), c, 0, 0, 0);
}
__device__ __forceinline__ f32x16 mfma32(short8 a, short8 b, f32x16 c) {
  return __builtin_amdgcn_mfma_f32_32x32x16_bf16(
      __builtin_bit_cast(bf16x8, a), __builtin_bit_cast(bf16x8, b), c, 0, 0, 0);
}
__device__ __forceinline__ void gload16(const void* g, void* l) {
  __builtin_amdgcn_global_load_lds(
      (const __attribute__((address_space(1))) unsigned int*)g,
      (__attribute__((address_space(3))) unsigned int*)l, 16, 0, 0);
}
__device__ __forceinline__ float vmax16(f32x16 v) {
  float a0 = fmaxf(v[0], v[1]),   a1 = fmaxf(v[2], v[3]);
  float a2 = fmaxf(v[4], v[5]),   a3 = fmaxf(v[6], v[7]);
  float a4 = fmaxf(v[8], v[9]),   a5 = fmaxf(v[10], v[11]);
  float a6 = fmaxf(v[12], v[13]), a7 = fmaxf(v[14], v[15]);
  float b0 = fmaxf(a0, a1), b1 = fmaxf(a2, a3), b2 = fmaxf(a4, a5), b3 = fmaxf(a6, a7);
  return fmaxf(fmaxf(b0, b1), fmaxf(b2, b3));
}
__device__ __forceinline__ float vsum16(f32x16 v) {
  float a0 = v[0]+v[1], a1 = v[2]+v[3], a2 = v[4]+v[5], a3 = v[6]+v[7];
  float a4 = v[8]+v[9], a5 = v[10]+v[11], a6 = v[12]+v[13], a7 = v[14]+v[15];
  return ((a0+a1)+(a2+a3)) + ((a4+a5)+(a6+a7));
}

// ---------------- merged preprocessing: cvt_x + transpose both W ----------------
__global__ __launch_bounds__(256) void prep_kernel(
    const float* __restrict__ x, short* __restrict__ xb,
    const float* __restrict__ Wqkv, short* __restrict__ wqkvT,
    const float* __restrict__ Wproj, short* __restrict__ wprojT) {
  __shared__ float tile[32][33];
  const int bid = blockIdx.x, tid = threadIdx.x;
  if (bid < 4096) {
    const size_t i = ((size_t)bid * 256 + tid) * 8;
    f32x4 a = *(const f32x4*)&x[i];
    f32x4 b = *(const f32x4*)&x[i + 4];
    short8 o;
    o[0]=f2b(a[0]); o[1]=f2b(a[1]); o[2]=f2b(a[2]); o[3]=f2b(a[3]);
    o[4]=f2b(b[0]); o[5]=f2b(b[1]); o[6]=f2b(b[2]); o[7]=f2b(b[3]);
    *(short8*)&xb[i] = o;
    return;
  }
  const float* in; short* out; int R, C, bx, by;
  if (bid < 4096 + 3072) {
    const int b2 = bid - 4096;
    in = Wqkv; out = wqkvT; R = Kn; C = N1; bx = b2 % 96; by = b2 / 96;
  } else {
    const int b3 = bid - 7168;
    in = Wproj; out = wprojT; R = Kn; C = En; bx = b3 % 32; by = b3 / 32;
  }
  const int c0 = bx * 32, r0 = by * 32;
  const int lr = tid >> 3, lc = (tid & 7) * 4;
  f32x4 v = *(const f32x4*)&in[(size_t)(r0 + lr) * C + c0 + lc];
  tile[lr][lc] = v[0]; tile[lr][lc+1] = v[1]; tile[lr][lc+2] = v[2]; tile[lr][lc+3] = v[3];
  __syncthreads();
  const int oc = tid >> 3, orr = (tid & 7) * 4;
  short4v ov;
  ov[0] = f2b(tile[orr][oc]);   ov[1] = f2b(tile[orr+1][oc]);
  ov[2] = f2b(tile[orr+2][oc]); ov[3] = f2b(tile[orr+3][oc]);
  *(short4v*)&out[(size_t)(c0 + oc) * R + r0 + orr] = ov;
}

// ---------------- GEMM (round-13 proven: fused LN + coalesced epilogue) ----------------
template<int MODE>
__global__ __launch_bounds__(256) void gemm_kernel(
    const short* __restrict__ A, const short* __restrict__ Bt,
    const float* __restrict__ bias, float* __restrict__ Cf,
    short* __restrict__ qo, short* __restrict__ ko2, short* __restrict__ vo,
    const float* __restrict__ qg, const float* __restrict__ qb,
    const float* __restrict__ kg, const float* __restrict__ kb,
    int N, int NBX, int cpx) {
  __shared__ short S[8192];
  const int lin = blockIdx.x;
  const int swz = (lin & 7) * cpx + (lin >> 3);
  const int bx = swz % NBX, by = swz / NBX;
  const int tid = threadIdx.x, lane = tid & 63, w = tid >> 6;
  const int rowBase = by * 128, colBase = bx * 128;
  f32x4 acc[4][4] = {};
  const int srow = tid >> 2, sk = (tid & 3) << 3;
  const short* Ag = A  + (size_t)(rowBase + srow) * Kn + sk;
  const short* Bg = Bt + (size_t)(colBase + srow) * Kn + sk;
  short* AsW = S + w * 512;
  short* BsW = S + 4096 + w * 512;
  const int ar = (w >> 1) * 64, bc = (w & 1) * 64;
  const int lg = lane >> 4, lg8 = lg * 8, lr = lane & 15;

  for (int kt = 0; kt < Kn; kt += 32) {
    __syncthreads();
    gload16(Ag + kt,            AsW);
    gload16(Ag + kt + 64 * Kn,  AsW + 2048);
    gload16(Bg + kt,            BsW);
    gload16(Bg + kt + 64 * Kn,  BsW + 2048);
    __syncthreads();
    short8 af[4], bfr[4];
#pragma unroll
    for (int m = 0; m < 4; ++m) af[m]  = *(const short8*)&S[(ar + m*16 + lr)*32 + lg8];
#pragma unroll
    for (int n = 0; n < 4; ++n) bfr[n] = *(const short8*)&S[4096 + (bc + n*16 + lr)*32 + lg8];
#pragma unroll
    for (int m = 0; m < 4; ++m)
#pragma unroll
      for (int n = 0; n < 4; ++n)
        acc[m][n] = mfma16(af[m], bfr[n], acc[m][n]);
  }

  const int gr0 = rowBase + ar + lg * 4;
  const int gc0 = colBase + bc + lr;

  float bb[4];
#pragma unroll
  for (int n = 0; n < 4; ++n) bb[n] = bias[gc0 + n * 16];
#pragma unroll
  for (int m = 0; m < 4; ++m)
#pragma unroll
    for (int n = 0; n < 4; ++n)
#pragma unroll
      for (int r = 0; r < 4; ++r) acc[m][n][r] += bb[n];

  if (MODE == 0) {
#pragma unroll
    for (int m = 0; m < 4; ++m)
#pragma unroll
      for (int n = 0; n < 4; ++n) {
        const int gc = gc0 + n * 16;
#pragma unroll
        for (int r = 0; r < 4; ++r)
          Cf[(size_t)(gr0 + m*16 + r) * N + gc] = acc[m][n][r];
      }
    return;
  }

  const int which = colBase >> 10;            // block-uniform: 0=q 1=k 2=v
  if (which < 2) {
    const float* gp = (which == 0) ? qg : kg;
    const float* bp = (which == 0) ? qb : kb;
    const float sc = (which == 0) ? 0.1803368801111204f : 1.0f;  // 0.125*log2(e)
    float gam[4], bet[4];
#pragma unroll
    for (int n = 0; n < 4; ++n) { gam[n] = gp[n * 16 + lr]; bet[n] = bp[n * 16 + lr]; }
#pragma unroll
    for (int m = 0; m < 4; ++m)
#pragma unroll
      for (int r = 0; r < 4; ++r) {
        float s1 = 0.f, s2 = 0.f;
#pragma unroll
        for (int n = 0; n < 4; ++n) {
          const float v = acc[m][n][r];
          s1 += v; s2 += v * v;
        }
#pragma unroll
        for (int off = 1; off < 16; off <<= 1) {
          s1 += __shfl_xor(s1, off);
          s2 += __shfl_xor(s2, off);
        }
        const float mu = s1 * 0.015625f;
        const float rs = rsqrtf(s2 * 0.015625f - mu * mu + 1e-5f);
#pragma unroll
        for (int n = 0; n < 4; ++n)
          acc[m][n][r] = ((acc[m][n][r] - mu) * rs * gam[n] + bet[n]) * sc;
      }
  }

  __syncthreads();
  short* Sw = S + w * 2048;
  const int t0 = (rowBase & 2047) + ar;
  const int bidx = (rowBase + ar) >> 11;
  const int hh = ((colBase + bc) & 1023) >> 6;
  const int bh = bidx * Hn + hh;
  const int l8 = lane & 7, ld8 = lane >> 3;

  if (which < 2) {
    short* dst0 = (which == 0) ? qo : ko2;
#pragma unroll
    for (int p = 0; p < 2; ++p) {
#pragma unroll
      for (int mm = 0; mm < 2; ++mm) {
        const int m = p * 2 + mm;
#pragma unroll
        for (int n = 0; n < 4; ++n)
#pragma unroll
          for (int r = 0; r < 4; ++r) {
            const int tl = mm*16 + lg*4 + r;
            const int dl = n*16 + lr;
            Sw[tl*64 + (dl ^ ((tl & 7) << 3))] = f2b(acc[m][n][r]);
          }
      }
#pragma unroll
      for (int i = 0; i < 4; ++i) {
        const int tl = i*8 + ld8;
        short8 v = *(const short8*)&Sw[tl*64 + ((l8*8) ^ ((tl & 7) << 3))];
        const int t = t0 + p*32 + tl;
        *(short8*)&dst0[((size_t)bh * Tn + t) * Dh + l8*8] = v;
      }
    }
  } else {
#pragma unroll
    for (int p = 0; p < 2; ++p) {
#pragma unroll
      for (int nn = 0; nn < 2; ++nn) {
        const int n = p * 2 + nn;
#pragma unroll
        for (int m = 0; m < 4; ++m)
#pragma unroll
          for (int r = 0; r < 4; ++r) {
            const int dl = nn*16 + lr;
            const int tc = m*16 + lg*4 + r;
            Sw[dl*64 + (tc ^ ((dl & 7) << 3))] = f2b(acc[m][n][r]);
          }
      }
#pragma unroll
      for (int i = 0; i < 4; ++i) {
        const int dl = i*8 + ld8;
        short8 v = *(const short8*)&Sw[dl*64 + ((l8*8) ^ ((dl & 7) << 3))];
        const int d = p*32 + dl;
        *(short8*)&vo[((size_t)bh * Dh + d) * Tn + t0 + l8*8] = v;
      }
    }
  }
}

// ---------------- Flash attention: swapped 32x32, shfl_xor-based exchange ----------------
// 1024 blocks (XCD-swizzled), 4 waves x 32 q-rows. S^T = mfma32(A=K, B=Q):
// lane holds P^T[k][q=l&31]; p[t][r] covers k = 32t + (r&3) + 8*(r>>2) + 4*hi.
// Operand maps verified-by-use (R2's QK produced correct softmax-normalized S).
// PV B-fragment built with __shfl_xor(.,32) + selects ONLY (no permlane/cvt_pk
// convention dependence). Derived slot table (hand-verified on 4 elements):
//   fragment f (k-base 32t+16f), rb=8f, ex[r]=shfl_xor(p[t][r],32):
//     j=0..3: hi==0 ? p[t][rb+j]  : ex[rb+4+j]
//     j=4..7: hi==0 ? ex[rb+j-4]  : p[t][rb+j]
// Softmax fully lane-local (q=l&31; both half-lanes share q -> one shfl_xor
// for cross-half max/sum). No P LDS traffic at all.
__global__ __launch_bounds__(256) void flash32_kernel(
    const short* __restrict__ qp, const short* __restrict__ kp,
    const short* __restrict__ vt, short* __restrict__ y) {
  __shared__ char lds[32768];          // K dbuf 2x8KB | Vt dbuf 2x8KB
  char* ldsK = lds;
  char* ldsV = lds + 16384;

  const int tid = threadIdx.x, l = tid & 63, w = tid >> 6;
  const int l31 = l & 31, hi = l >> 5;

  // XCD swizzle (bijective over 1024 = 8 xcd x 8 bh x 16 qt)
  const int j0 = blockIdx.x;
  const int xcd = j0 & 7, kk0 = j0 >> 3;
  const int bh = 8 * xcd + (kk0 & 7), qt = kk0 >> 3;

  const int qrow0 = qt * 128 + w * 32;
  const short* qrow = qp + ((size_t)bh * Tn + qrow0 + l31) * Dh;
  short8 qf[4];
#pragma unroll
  for (int c = 0; c < 4; ++c)
    qf[c] = *(const short8*)&qrow[c * 16 + hi * 8];

  f32x16 o[2] = {};
  float m = -1e30f, lsum = 0.f;

  const char* kb2 = (const char*)(kp + (size_t)bh * Tn * Dh);
  const char* vb2 = (const char*)(vt + (size_t)bh * Dh * Tn);
  const int sr0 = tid >> 3;            // 0..31
  const int colb = (tid & 7) << 4;     // bytes 0..112

#define STAGE(jt, bsel)                                                          \
  {                                                                              \
    _Pragma("unroll")                                                            \
    for (int i = 0; i < 2; ++i) {                                                \
      const int row = i * 32 + sr0;                                              \
      const int sw = colb ^ ((row & 7) << 4);                                    \
      gload16(kb2 + (size_t)((jt) * 64 + row) * 128 + sw,                        \
              ldsK + (bsel) * 8192 + i * 4096 + tid * 16);                       \
      gload16(vb2 + (size_t)row * (Tn * 2) + (size_t)(jt) * 128 + sw,            \
              ldsV + (bsel) * 8192 + i * 4096 + tid * 16);                       \
    }                                                                            \
  }

  STAGE(0, 0);
  __syncthreads();

  for (int j = 0; j < Tn / 64; ++j) {
    const int cur = j & 1;
    if (j + 1 < Tn / 64) STAGE(j + 1, cur ^ 1);

    const char* Kb = ldsK + cur * 8192;
    const char* Vb = ldsV + cur * 8192;

    // S^T = K * Q^T
    f32x16 p[2] = {};
    __builtin_amdgcn_s_setprio(1);
#pragma unroll
    for (int t = 0; t < 2; ++t) {
      const int row = t * 32 + l31;
#pragma unroll
      for (int c = 0; c < 4; ++c) {
        short8 a = *(const short8*)(Kb + row * 128 + ((c * 32 + hi * 16) ^ ((row & 7) << 4)));
        p[t] = mfma32(a, qf[c], p[t]);
      }
    }
    __builtin_amdgcn_s_setprio(0);

    // lane-local online softmax (exp2 domain; scale folded in GEMM1-LN)
    float mx = fmaxf(vmax16(p[0]), vmax16(p[1]));
    mx = fmaxf(mx, __shfl_xor(mx, 32));
    if (!__all(mx - m <= 11.0f)) {
      const float mn = fmaxf(m, mx);
      const float corr = __builtin_amdgcn_exp2f(m - mn);
      lsum *= corr;
      o[0] *= corr;
      o[1] *= corr;
      m = mn;
    }
#pragma unroll
    for (int t = 0; t < 2; ++t)
#pragma unroll
      for (int e = 0; e < 16; ++e)
        p[t][e] = __builtin_amdgcn_exp2f(p[t][e] - m);
    {
      float ps = vsum16(p[0]) + vsum16(p[1]);
      lsum += ps + __shfl_xor(ps, 32);
    }

    // build PV B-fragments via shfl_xor + select + bit-pack (truncation)
    short8 pf[4];
#pragma unroll
    for (int t = 0; t < 2; ++t) {
      float ex[16];
#pragma unroll
      for (int r = 0; r < 16; ++r) ex[r] = __shfl_xor(p[t][r], 32);
#pragma unroll
      for (int f = 0; f < 2; ++f) {
        const int rb = 8 * f;
        float sl[8];
#pragma unroll
        for (int jj = 0; jj < 4; ++jj) sl[jj]     = (hi == 0) ? p[t][rb + jj]     : ex[rb + 4 + jj];
#pragma unroll
        for (int jj = 4; jj < 8; ++jj) sl[jj]     = (hi == 0) ? ex[rb + jj - 4]   : p[t][rb + jj];
        i32x4 wv;
#pragma unroll
        for (int i = 0; i < 4; ++i) {
          const unsigned lo = __builtin_bit_cast(unsigned, sl[2*i])     >> 16;
          const unsigned hw = __builtin_bit_cast(unsigned, sl[2*i + 1]) & 0xffff0000u;
          wv[i] = (int)(hw | lo);
        }
        pf[2*t + f] = __builtin_bit_cast(short8, wv);
      }
    }

    // O^T += V^T * P^T  (A=V^T, same map as K in QK; B=pf)
    __builtin_amdgcn_s_setprio(1);
#pragma unroll
    for (int dt = 0; dt < 2; ++dt) {
      const int row = dt * 32 + l31;
#pragma unroll
      for (int c = 0; c < 4; ++c) {
        short8 a = *(const short8*)(Vb + row * 128 + ((c * 32 + hi * 16) ^ ((row & 7) << 4)));
        o[dt] = mfma32(a, pf[c], o[dt]);
      }
    }
    __builtin_amdgcn_s_setprio(0);

    __syncthreads();
  }
#undef STAGE

  // epilogue: lane-local normalize, direct 8B stores
  // o[dt][4g+i] -> d = dt*32 + 8g + 4hi + i ; row t = qrow0 + l31
  const float rl = 1.0f / lsum;
  const int b = bh >> 4, hh = bh & 15;
  const int t = qrow0 + l31;
  short* yrow = y + ((size_t)(b * Tn + t)) * En + hh * 64;
#pragma unroll
  for (int dt = 0; dt < 2; ++dt)
#pragma unroll
    for (int g = 0; g < 4; ++g) {
      short4v v4;
#pragma unroll
      for (int i = 0; i < 4; ++i) v4[i] = f2b(o[dt][g*4 + i] * rl);
      *(short4v*)&yrow[dt*32 + g*8 + hi*4] = v4;
    }
}

extern "C" void kernel_launch(void* const* d_in, const int* in_sizes, int n_in,
                              void* d_out, int out_size, void* d_ws, size_t ws_size,
                              hipStream_t stream) {
  const float* x     = (const float*)d_in[0];
  const float* Wqkv  = (const float*)d_in[1];
  const float* bqkv  = (const float*)d_in[2];
  const float* qg    = (const float*)d_in[3];
  const float* qb    = (const float*)d_in[4];
  const float* kg    = (const float*)d_in[5];
  const float* kb    = (const float*)d_in[6];
  const float* Wproj = (const float*)d_in[7];
  const float* bproj = (const float*)d_in[8];
  float* out = (float*)d_out;

  char* p = (char*)d_ws;
  short* xb     = (short*)p; p += (size_t)Mn * Kn * 2;
  short* wqkvT  = (short*)p; p += (size_t)N1 * Kn * 2;
  short* wprojT = (short*)p; p += (size_t)En * Kn * 2;
  short* qp     = (short*)p; p += (size_t)Mn * Kn * 2;
  short* kp     = (short*)p; p += (size_t)Mn * Kn * 2;
  short* vtb    = (short*)p; p += (size_t)Mn * Kn * 2;
  short* yb     = (short*)p; p += (size_t)Mn * Kn * 2;

  prep_kernel<<<8192, 256, 0, stream>>>(x, xb, Wqkv, wqkvT, Wproj, wprojT);
  gemm_kernel<1><<<(N1 / 128) * (Mn / 128), 256, 0, stream>>>(
      xb, wqkvT, bqkv, nullptr, qp, kp, vtb, qg, qb, kg, kb,
      N1, N1 / 128, (N1 / 128) * (Mn / 128) / 8);
  flash32_kernel<<<1024, 256, 0, stream>>>(qp, kp, vtb, yb);
  gemm_kernel<0><<<(En / 128) * (Mn / 128), 256, 0, stream>>>(
      yb, wprojT, bproj, out, nullptr, nullptr, nullptr, nullptr, nullptr, nullptr, nullptr,
      En, En / 128, (En / 128) * (Mn / 128) / 8);
}

// Round 15
// 254.675 us; speedup vs baseline: 1.0100x; 1.0100x over previous
//
#include <hip/hip_runtime.h>

// Problem constants
#define Hn  16
#define Dh  64
#define Bb  4
#define Tn  2048
#define En  1024
#define Mn  8192           // B*T
#define N1  3072           // 3*E
#define Kn  1024           // E

typedef __attribute__((ext_vector_type(8)))  short  short8;
typedef __attribute__((ext_vector_type(4)))  short  short4v;
typedef __attribute__((ext_vector_type(4)))  float  f32x4;
typedef __attribute__((ext_vector_type(16))) float  f32x16;
typedef __attribute__((ext_vector_type(8)))  __bf16 bf16x8;
typedef __attribute__((ext_vector_type(4)))  int    i32x4;

__device__ __forceinline__ float b2f(short s) {
  unsigned u = ((unsigned)(unsigned short)s) << 16;
  return __builtin_bit_cast(float, u);
}
__device__ __forceinline__ short f2b(float f) {
  unsigned u = __builtin_bit_cast(unsigned, f);
  u += 0x7fffu + ((u >> 16) & 1u);
  return (short)(u >> 16);
}
__device__ __forceinline__ f32x4 mfma16(short8 a, short8 b, f32x4 c) {
  return __builtin_amdgcn_mfma_f32_16x16x32_bf16(
      __builtin_bit_cast(bf16x8, a), __builtin_bit_cast(bf16x8, b), c, 0, 0, 0);
}
__device__ __forceinline__ f32x16 mfma32(short8 a, short8 b, f32x16 c) {
  return __builtin_amdgcn_mfma_f32_32x32x16_bf16(
      __builtin_bit_cast(bf16x8, a), __builtin_bit_cast(bf16x8, b), c, 0, 0, 0);
}
__device__ __forceinline__ void gload16(const void* g, void* l) {
  __builtin_amdgcn_global_load_lds(
      (const __attribute__((address_space(1))) unsigned int*)g,
      (__attribute__((address_space(3))) unsigned int*)l, 16, 0, 0);
}
__device__ __forceinline__ float vmax16(f32x16 v) {
  float a0 = fmaxf(v[0], v[1]),   a1 = fmaxf(v[2], v[3]);
  float a2 = fmaxf(v[4], v[5]),   a3 = fmaxf(v[6], v[7]);
  float a4 = fmaxf(v[8], v[9]),   a5 = fmaxf(v[10], v[11]);
  float a6 = fmaxf(v[12], v[13]), a7 = fmaxf(v[14], v[15]);
  float b0 = fmaxf(a0, a1), b1 = fmaxf(a2, a3), b2 = fmaxf(a4, a5), b3 = fmaxf(a6, a7);
  return fmaxf(fmaxf(b0, b1), fmaxf(b2, b3));
}
__device__ __forceinline__ float vsum16(f32x16 v) {
  float a0 = v[0]+v[1], a1 = v[2]+v[3], a2 = v[4]+v[5], a3 = v[6]+v[7];
  float a4 = v[8]+v[9], a5 = v[10]+v[11], a6 = v[12]+v[13], a7 = v[14]+v[15];
  return ((a0+a1)+(a2+a3)) + ((a4+a5)+(a6+a7));
}

// ---------------- merged preprocessing: cvt_x + transpose both W ----------------
__global__ __launch_bounds__(256) void prep_kernel(
    const float* __restrict__ x, short* __restrict__ xb,
    const float* __restrict__ Wqkv, short* __restrict__ wqkvT,
    const float* __restrict__ Wproj, short* __restrict__ wprojT) {
  __shared__ float tile[32][33];
  const int bid = blockIdx.x, tid = threadIdx.x;
  if (bid < 4096) {
    const size_t i = ((size_t)bid * 256 + tid) * 8;
    f32x4 a = *(const f32x4*)&x[i];
    f32x4 b = *(const f32x4*)&x[i + 4];
    short8 o;
    o[0]=f2b(a[0]); o[1]=f2b(a[1]); o[2]=f2b(a[2]); o[3]=f2b(a[3]);
    o[4]=f2b(b[0]); o[5]=f2b(b[1]); o[6]=f2b(b[2]); o[7]=f2b(b[3]);
    *(short8*)&xb[i] = o;
    return;
  }
  const float* in; short* out; int R, C, bx, by;
  if (bid < 4096 + 3072) {
    const int b2 = bid - 4096;
    in = Wqkv; out = wqkvT; R = Kn; C = N1; bx = b2 % 96; by = b2 / 96;
  } else {
    const int b3 = bid - 7168;
    in = Wproj; out = wprojT; R = Kn; C = En; bx = b3 % 32; by = b3 / 32;
  }
  const int c0 = bx * 32, r0 = by * 32;
  const int lr = tid >> 3, lc = (tid & 7) * 4;
  f32x4 v = *(const f32x4*)&in[(size_t)(r0 + lr) * C + c0 + lc];
  tile[lr][lc] = v[0]; tile[lr][lc+1] = v[1]; tile[lr][lc+2] = v[2]; tile[lr][lc+3] = v[3];
  __syncthreads();
  const int oc = tid >> 3, orr = (tid & 7) * 4;
  short4v ov;
  ov[0] = f2b(tile[orr][oc]);   ov[1] = f2b(tile[orr+1][oc]);
  ov[2] = f2b(tile[orr+2][oc]); ov[3] = f2b(tile[orr+3][oc]);
  *(short4v*)&out[(size_t)(c0 + oc) * R + r0 + orr] = ov;
}

// ---------------- GEMM (round-13 proven: fused LN + coalesced epilogue) ----------------
template<int MODE>
__global__ __launch_bounds__(256) void gemm_kernel(
    const short* __restrict__ A, const short* __restrict__ Bt,
    const float* __restrict__ bias, float* __restrict__ Cf,
    short* __restrict__ qo, short* __restrict__ ko2, short* __restrict__ vo,
    const float* __restrict__ qg, const float* __restrict__ qb,
    const float* __restrict__ kg, const float* __restrict__ kb,
    int N, int NBX, int cpx) {
  __shared__ short S[8192];
  const int lin = blockIdx.x;
  const int swz = (lin & 7) * cpx + (lin >> 3);
  const int bx = swz % NBX, by = swz / NBX;
  const int tid = threadIdx.x, lane = tid & 63, w = tid >> 6;
  const int rowBase = by * 128, colBase = bx * 128;
  f32x4 acc[4][4] = {};
  const int srow = tid >> 2, sk = (tid & 3) << 3;
  const short* Ag = A  + (size_t)(rowBase + srow) * Kn + sk;
  const short* Bg = Bt + (size_t)(colBase + srow) * Kn + sk;
  short* AsW = S + w * 512;
  short* BsW = S + 4096 + w * 512;
  const int ar = (w >> 1) * 64, bc = (w & 1) * 64;
  const int lg = lane >> 4, lg8 = lg * 8, lr = lane & 15;

  for (int kt = 0; kt < Kn; kt += 32) {
    __syncthreads();
    gload16(Ag + kt,            AsW);
    gload16(Ag + kt + 64 * Kn,  AsW + 2048);
    gload16(Bg + kt,            BsW);
    gload16(Bg + kt + 64 * Kn,  BsW + 2048);
    __syncthreads();
    short8 af[4], bfr[4];
#pragma unroll
    for (int m = 0; m < 4; ++m) af[m]  = *(const short8*)&S[(ar + m*16 + lr)*32 + lg8];
#pragma unroll
    for (int n = 0; n < 4; ++n) bfr[n] = *(const short8*)&S[4096 + (bc + n*16 + lr)*32 + lg8];
#pragma unroll
    for (int m = 0; m < 4; ++m)
#pragma unroll
      for (int n = 0; n < 4; ++n)
        acc[m][n] = mfma16(af[m], bfr[n], acc[m][n]);
  }

  const int gr0 = rowBase + ar + lg * 4;
  const int gc0 = colBase + bc + lr;

  float bb[4];
#pragma unroll
  for (int n = 0; n < 4; ++n) bb[n] = bias[gc0 + n * 16];
#pragma unroll
  for (int m = 0; m < 4; ++m)
#pragma unroll
    for (int n = 0; n < 4; ++n)
#pragma unroll
      for (int r = 0; r < 4; ++r) acc[m][n][r] += bb[n];

  if (MODE == 0) {
#pragma unroll
    for (int m = 0; m < 4; ++m)
#pragma unroll
      for (int n = 0; n < 4; ++n) {
        const int gc = gc0 + n * 16;
#pragma unroll
        for (int r = 0; r < 4; ++r)
          Cf[(size_t)(gr0 + m*16 + r) * N + gc] = acc[m][n][r];
      }
    return;
  }

  const int which = colBase >> 10;            // block-uniform: 0=q 1=k 2=v
  if (which < 2) {
    const float* gp = (which == 0) ? qg : kg;
    const float* bp = (which == 0) ? qb : kb;
    const float sc = (which == 0) ? 0.1803368801111204f : 1.0f;  // 0.125*log2(e)
    float gam[4], bet[4];
#pragma unroll
    for (int n = 0; n < 4; ++n) { gam[n] = gp[n * 16 + lr]; bet[n] = bp[n * 16 + lr]; }
#pragma unroll
    for (int m = 0; m < 4; ++m)
#pragma unroll
      for (int r = 0; r < 4; ++r) {
        float s1 = 0.f, s2 = 0.f;
#pragma unroll
        for (int n = 0; n < 4; ++n) {
          const float v = acc[m][n][r];
          s1 += v; s2 += v * v;
        }
#pragma unroll
        for (int off = 1; off < 16; off <<= 1) {
          s1 += __shfl_xor(s1, off);
          s2 += __shfl_xor(s2, off);
        }
        const float mu = s1 * 0.015625f;
        const float rs = rsqrtf(s2 * 0.015625f - mu * mu + 1e-5f);
#pragma unroll
        for (int n = 0; n < 4; ++n)
          acc[m][n][r] = ((acc[m][n][r] - mu) * rs * gam[n] + bet[n]) * sc;
      }
  }

  __syncthreads();
  short* Sw = S + w * 2048;
  const int t0 = (rowBase & 2047) + ar;
  const int bidx = (rowBase + ar) >> 11;
  const int hh = ((colBase + bc) & 1023) >> 6;
  const int bh = bidx * Hn + hh;
  const int l8 = lane & 7, ld8 = lane >> 3;

  if (which < 2) {
    short* dst0 = (which == 0) ? qo : ko2;
#pragma unroll
    for (int p = 0; p < 2; ++p) {
#pragma unroll
      for (int mm = 0; mm < 2; ++mm) {
        const int m = p * 2 + mm;
#pragma unroll
        for (int n = 0; n < 4; ++n)
#pragma unroll
          for (int r = 0; r < 4; ++r) {
            const int tl = mm*16 + lg*4 + r;
            const int dl = n*16 + lr;
            Sw[tl*64 + (dl ^ ((tl & 7) << 3))] = f2b(acc[m][n][r]);
          }
      }
#pragma unroll
      for (int i = 0; i < 4; ++i) {
        const int tl = i*8 + ld8;
        short8 v = *(const short8*)&Sw[tl*64 + ((l8*8) ^ ((tl & 7) << 3))];
        const int t = t0 + p*32 + tl;
        *(short8*)&dst0[((size_t)bh * Tn + t) * Dh + l8*8] = v;
      }
    }
  } else {
#pragma unroll
    for (int p = 0; p < 2; ++p) {
#pragma unroll
      for (int nn = 0; nn < 2; ++nn) {
        const int n = p * 2 + nn;
#pragma unroll
        for (int m = 0; m < 4; ++m)
#pragma unroll
          for (int r = 0; r < 4; ++r) {
            const int dl = nn*16 + lr;
            const int tc = m*16 + lg*4 + r;
            Sw[dl*64 + (tc ^ ((dl & 7) << 3))] = f2b(acc[m][n][r]);
          }
      }
#pragma unroll
      for (int i = 0; i < 4; ++i) {
        const int dl = i*8 + ld8;
        short8 v = *(const short8*)&Sw[dl*64 + ((l8*8) ^ ((dl & 7) << 3))];
        const int d = p*32 + dl;
        *(short8*)&vo[((size_t)bh * Dh + d) * Tn + t0 + l8*8] = v;
      }
    }
  }
}

// ---------------- Flash attention: swapped 32x32 (R14-verified numerics) ----------------
// Round-15 fixes (layout/traffic only, values identical to R14):
// (1) Full-row LDS swizzle swz8(row) = (row&7) ^ ((row>>3)<<1), applied as
//     granule-XOR on BOTH the pre-swizzled global source and the read address
//     (same involution). R14's (row&7)-only swizzle left lanes {r,r+8,r+16,
//     r+24} in the same 16B slot -> 4-way bank conflict (8.4M/dispatch);
//     swz8 makes every read group uniform-8 across bank-groups (the same
//     structure the 16x16 kernel measured at 0 conflicts).
// (2) Pre-selected exchange: send (hi ? p[r'] : p[r'+4]) through
//     __shfl_xor(.,32) so each half transmits exactly what the other needs:
//     16 shfls/tile instead of 32. Slot table unchanged from R14:
//       hi=0: sl[0..3]=p[rb+0..3],  sl[4..7]=recv[rb'=0..3]   (partner p[rb+0..3])
//       hi=1: sl[0..3]=recv[0..3] (partner p[rb+4..7]), sl[4..7]=p[rb+4..7]
__global__ __launch_bounds__(256) void flash32_kernel(
    const short* __restrict__ qp, const short* __restrict__ kp,
    const short* __restrict__ vt, short* __restrict__ y) {
  __shared__ char lds[32768];          // K dbuf 2x8KB | Vt dbuf 2x8KB
  char* ldsK = lds;
  char* ldsV = lds + 16384;

  const int tid = threadIdx.x, l = tid & 63, w = tid >> 6;
  const int l31 = l & 31, hi = l >> 5;

  // XCD swizzle (bijective over 1024 = 8 xcd x 8 bh x 16 qt)
  const int j0 = blockIdx.x;
  const int xcd = j0 & 7, kk0 = j0 >> 3;
  const int bh = 8 * xcd + (kk0 & 7), qt = kk0 >> 3;

  const int qrow0 = qt * 128 + w * 32;
  const short* qrow = qp + ((size_t)bh * Tn + qrow0 + l31) * Dh;
  short8 qf[4];
#pragma unroll
  for (int c = 0; c < 4; ++c)
    qf[c] = *(const short8*)&qrow[c * 16 + hi * 8];

  f32x16 o[2] = {};
  float m = -1e30f, lsum = 0.f;

  const char* kb2 = (const char*)(kp + (size_t)bh * Tn * Dh);
  const char* vb2 = (const char*)(vt + (size_t)bh * Dh * Tn);
  const int sr0 = tid >> 3;            // 0..31 (row within 32-row half)
  // full-row swizzle, bytes (per-lane constant): stage side
  const int swzst = (((sr0 & 7) ^ ((sr0 >> 3) << 1)) << 4);
  const int colb = (tid & 7) << 4;
  // read side (row = {t,dt}*32 + l31; (row>>3)&3 == l31>>3 since t*4 % 4 == 0)
  const int swzrd = (((l31 & 7) ^ ((l31 >> 3) << 1)) << 4);

#define STAGE(jt, bsel)                                                          \
  {                                                                              \
    _Pragma("unroll")                                                            \
    for (int i = 0; i < 2; ++i) {                                                \
      const int row = i * 32 + sr0;                                              \
      const int sw = colb ^ swzst;                                               \
      gload16(kb2 + (size_t)((jt) * 64 + row) * 128 + sw,                        \
              ldsK + (bsel) * 8192 + i * 4096 + tid * 16);                       \
      gload16(vb2 + (size_t)row * (Tn * 2) + (size_t)(jt) * 128 + sw,            \
              ldsV + (bsel) * 8192 + i * 4096 + tid * 16);                       \
    }                                                                            \
  }

  STAGE(0, 0);
  __syncthreads();

  for (int j = 0; j < Tn / 64; ++j) {
    const int cur = j & 1;
    if (j + 1 < Tn / 64) STAGE(j + 1, cur ^ 1);

    const char* Kb = ldsK + cur * 8192;
    const char* Vb = ldsV + cur * 8192;

    // S^T = K * Q^T
    f32x16 p[2] = {};
    __builtin_amdgcn_s_setprio(1);
#pragma unroll
    for (int t = 0; t < 2; ++t) {
      const int row = t * 32 + l31;
#pragma unroll
      for (int c = 0; c < 4; ++c) {
        short8 a = *(const short8*)(Kb + row * 128 + ((c * 32 + hi * 16) ^ swzrd));
        p[t] = mfma32(a, qf[c], p[t]);
      }
    }
    __builtin_amdgcn_s_setprio(0);

    // lane-local online softmax (exp2 domain; scale folded in GEMM1-LN)
    float mx = fmaxf(vmax16(p[0]), vmax16(p[1]));
    mx = fmaxf(mx, __shfl_xor(mx, 32));
    if (!__all(mx - m <= 11.0f)) {
      const float mn = fmaxf(m, mx);
      const float corr = __builtin_amdgcn_exp2f(m - mn);
      lsum *= corr;
      o[0] *= corr;
      o[1] *= corr;
      m = mn;
    }
#pragma unroll
    for (int t = 0; t < 2; ++t)
#pragma unroll
      for (int e = 0; e < 16; ++e)
        p[t][e] = __builtin_amdgcn_exp2f(p[t][e] - m);
    {
      float ps = vsum16(p[0]) + vsum16(p[1]);
      lsum += ps + __shfl_xor(ps, 32);
    }

    // build PV B-fragments: pre-selected shfl (8 per t), select, bit-pack
    short8 pf[4];
#pragma unroll
    for (int t = 0; t < 2; ++t) {
      float recv[8];   // [f*4 + r']: partner's p[t][8f + (hi?4+r' : r')]... see table
#pragma unroll
      for (int f = 0; f < 2; ++f)
#pragma unroll
        for (int rp = 0; rp < 4; ++rp) {
          const float send = hi ? p[t][8*f + rp] : p[t][8*f + 4 + rp];
          recv[f*4 + rp] = __shfl_xor(send, 32);
        }
#pragma unroll
      for (int f = 0; f < 2; ++f) {
        const int rb = 8 * f;
        float sl[8];
#pragma unroll
        for (int jj = 0; jj < 4; ++jj) sl[jj]   = (hi == 0) ? p[t][rb + jj]     : recv[f*4 + jj];
#pragma unroll
        for (int jj = 0; jj < 4; ++jj) sl[4+jj] = (hi == 0) ? recv[f*4 + jj]   : p[t][rb + 4 + jj];
        i32x4 wv;
#pragma unroll
        for (int i = 0; i < 4; ++i) {
          const unsigned lo = __builtin_bit_cast(unsigned, sl[2*i])     >> 16;
          const unsigned hw = __builtin_bit_cast(unsigned, sl[2*i + 1]) & 0xffff0000u;
          wv[i] = (int)(hw | lo);
        }
        pf[2*t + f] = __builtin_bit_cast(short8, wv);
      }
    }

    // O^T += V^T * P^T
    __builtin_amdgcn_s_setprio(1);
#pragma unroll
    for (int dt = 0; dt < 2; ++dt) {
      const int row = dt * 32 + l31;
#pragma unroll
      for (int c = 0; c < 4; ++c) {
        short8 a = *(const short8*)(Vb + row * 128 + ((c * 32 + hi * 16) ^ swzrd));
        o[dt] = mfma32(a, pf[c], o[dt]);
      }
    }
    __builtin_amdgcn_s_setprio(0);

    __syncthreads();
  }
#undef STAGE

  // epilogue: lane-local normalize, direct 8B stores
  const float rl = 1.0f / lsum;
  const int b = bh >> 4, hh = bh & 15;
  const int t = qrow0 + l31;
  short* yrow = y + ((size_t)(b * Tn + t)) * En + hh * 64;
#pragma unroll
  for (int dt = 0; dt < 2; ++dt)
#pragma unroll
    for (int g = 0; g < 4; ++g) {
      short4v v4;
#pragma unroll
      for (int i = 0; i < 4; ++i) v4[i] = f2b(o[dt][g*4 + i] * rl);
      *(short4v*)&yrow[dt*32 + g*8 + hi*4] = v4;
    }
}

extern "C" void kernel_launch(void* const* d_in, const int* in_sizes, int n_in,
                              void* d_out, int out_size, void* d_ws, size_t ws_size,
                              hipStream_t stream) {
  const float* x     = (const float*)d_in[0];
  const float* Wqkv  = (const float*)d_in[1];
  const float* bqkv  = (const float*)d_in[2];
  const float* qg    = (const float*)d_in[3];
  const float* qb    = (const float*)d_in[4];
  const float* kg    = (const float*)d_in[5];
  const float* kb    = (const float*)d_in[6];
  const float* Wproj = (const float*)d_in[7];
  const float* bproj = (const float*)d_in[8];
  float* out = (float*)d_out;

  char* p = (char*)d_ws;
  short* xb     = (short*)p; p += (size_t)Mn * Kn * 2;
  short* wqkvT  = (short*)p; p += (size_t)N1 * Kn * 2;
  short* wprojT = (short*)p; p += (size_t)En * Kn * 2;
  short* qp     = (short*)p; p += (size_t)Mn * Kn * 2;
  short* kp     = (short*)p; p += (size_t)Mn * Kn * 2;
  short* vtb    = (short*)p; p += (size_t)Mn * Kn * 2;
  short* yb     = (short*)p; p += (size_t)Mn * Kn * 2;

  prep_kernel<<<8192, 256, 0, stream>>>(x, xb, Wqkv, wqkvT, Wproj, wprojT);
  gemm_kernel<1><<<(N1 / 128) * (Mn / 128), 256, 0, stream>>>(
      xb, wqkvT, bqkv, nullptr, qp, kp, vtb, qg, qb, kg, kb,
      N1, N1 / 128, (N1 / 128) * (Mn / 128) / 8);
  flash32_kernel<<<1024, 256, 0, stream>>>(qp, kp, vtb, yb);
  gemm_kernel<0><<<(En / 128) * (Mn / 128), 256, 0, stream>>>(
      yb, wprojT, bproj, out, nullptr, nullptr, nullptr, nullptr, nullptr, nullptr, nullptr,
      En, En / 128, (En / 128) * (Mn / 128) / 8);
}

// Round 16
// 240.135 us; speedup vs baseline: 1.0711x; 1.0605x over previous
//
#include <hip/hip_runtime.h>

// Problem constants
#define Hn  16
#define Dh  64
#define Bb  4
#define Tn  2048
#define En  1024
#define Mn  8192           // B*T
#define N1  3072           // 3*E
#define Kn  1024           // E

typedef __attribute__((ext_vector_type(8)))  short  short8;
typedef __attribute__((ext_vector_type(4)))  short  short4v;
typedef __attribute__((ext_vector_type(4)))  float  f32x4;
typedef __attribute__((ext_vector_type(16))) float  f32x16;
typedef __attribute__((ext_vector_type(8)))  __bf16 bf16x8;
typedef __attribute__((ext_vector_type(4)))  int    i32x4;

__device__ __forceinline__ float b2f(short s) {
  unsigned u = ((unsigned)(unsigned short)s) << 16;
  return __builtin_bit_cast(float, u);
}
__device__ __forceinline__ short f2b(float f) {
  unsigned u = __builtin_bit_cast(unsigned, f);
  u += 0x7fffu + ((u >> 16) & 1u);
  return (short)(u >> 16);
}
__device__ __forceinline__ f32x4 mfma16(short8 a, short8 b, f32x4 c) {
  return __builtin_amdgcn_mfma_f32_16x16x32_bf16(
      __builtin_bit_cast(bf16x8, a), __builtin_bit_cast(bf16x8, b), c, 0, 0, 0);
}
__device__ __forceinline__ f32x16 mfma32(short8 a, short8 b, f32x16 c) {
  return __builtin_amdgcn_mfma_f32_32x32x16_bf16(
      __builtin_bit_cast(bf16x8, a), __builtin_bit_cast(bf16x8, b), c, 0, 0, 0);
}
__device__ __forceinline__ void gload16(const void* g, void* l) {
  __builtin_amdgcn_global_load_lds(
      (const __attribute__((address_space(1))) unsigned int*)g,
      (__attribute__((address_space(3))) unsigned int*)l, 16, 0, 0);
}
// pack two f32 into (hi16(b)<<16 | hi16(a)) with one v_perm_b32 — bit-identical
// to the shift/and/or truncation pack
__device__ __forceinline__ unsigned packtrunc(float a, float b) {
  return __builtin_amdgcn_perm(__builtin_bit_cast(unsigned, b),
                               __builtin_bit_cast(unsigned, a), 0x07060302u);
}
__device__ __forceinline__ float vmax16(f32x16 v) {
  float a0 = fmaxf(v[0], v[1]),   a1 = fmaxf(v[2], v[3]);
  float a2 = fmaxf(v[4], v[5]),   a3 = fmaxf(v[6], v[7]);
  float a4 = fmaxf(v[8], v[9]),   a5 = fmaxf(v[10], v[11]);
  float a6 = fmaxf(v[12], v[13]), a7 = fmaxf(v[14], v[15]);
  float b0 = fmaxf(a0, a1), b1 = fmaxf(a2, a3), b2 = fmaxf(a4, a5), b3 = fmaxf(a6, a7);
  return fmaxf(fmaxf(b0, b1), fmaxf(b2, b3));
}
__device__ __forceinline__ float vsum16(f32x16 v) {
  float a0 = v[0]+v[1], a1 = v[2]+v[3], a2 = v[4]+v[5], a3 = v[6]+v[7];
  float a4 = v[8]+v[9], a5 = v[10]+v[11], a6 = v[12]+v[13], a7 = v[14]+v[15];
  return ((a0+a1)+(a2+a3)) + ((a4+a5)+(a6+a7));
}

// ---------------- merged preprocessing: cvt_x + transpose both W ----------------
__global__ __launch_bounds__(256) void prep_kernel(
    const float* __restrict__ x, short* __restrict__ xb,
    const float* __restrict__ Wqkv, short* __restrict__ wqkvT,
    const float* __restrict__ Wproj, short* __restrict__ wprojT) {
  __shared__ float tile[32][33];
  const int bid = blockIdx.x, tid = threadIdx.x;
  if (bid < 4096) {
    const size_t i = ((size_t)bid * 256 + tid) * 8;
    f32x4 a = *(const f32x4*)&x[i];
    f32x4 b = *(const f32x4*)&x[i + 4];
    short8 o;
    o[0]=f2b(a[0]); o[1]=f2b(a[1]); o[2]=f2b(a[2]); o[3]=f2b(a[3]);
    o[4]=f2b(b[0]); o[5]=f2b(b[1]); o[6]=f2b(b[2]); o[7]=f2b(b[3]);
    *(short8*)&xb[i] = o;
    return;
  }
  const float* in; short* out; int R, C, bx, by;
  if (bid < 4096 + 3072) {
    const int b2 = bid - 4096;
    in = Wqkv; out = wqkvT; R = Kn; C = N1; bx = b2 % 96; by = b2 / 96;
  } else {
    const int b3 = bid - 7168;
    in = Wproj; out = wprojT; R = Kn; C = En; bx = b3 % 32; by = b3 / 32;
  }
  const int c0 = bx * 32, r0 = by * 32;
  const int lr = tid >> 3, lc = (tid & 7) * 4;
  f32x4 v = *(const f32x4*)&in[(size_t)(r0 + lr) * C + c0 + lc];
  tile[lr][lc] = v[0]; tile[lr][lc+1] = v[1]; tile[lr][lc+2] = v[2]; tile[lr][lc+3] = v[3];
  __syncthreads();
  const int oc = tid >> 3, orr = (tid & 7) * 4;
  short4v ov;
  ov[0] = f2b(tile[orr][oc]);   ov[1] = f2b(tile[orr+1][oc]);
  ov[2] = f2b(tile[orr+2][oc]); ov[3] = f2b(tile[orr+3][oc]);
  *(short4v*)&out[(size_t)(c0 + oc) * R + r0 + orr] = ov;
}

// ---------------- GEMM (round-13 proven: fused LN + coalesced epilogue) ----------------
template<int MODE>
__global__ __launch_bounds__(256) void gemm_kernel(
    const short* __restrict__ A, const short* __restrict__ Bt,
    const float* __restrict__ bias, float* __restrict__ Cf,
    short* __restrict__ qo, short* __restrict__ ko2, short* __restrict__ vo,
    const float* __restrict__ qg, const float* __restrict__ qb,
    const float* __restrict__ kg, const float* __restrict__ kb,
    int N, int NBX, int cpx) {
  __shared__ short S[8192];
  const int lin = blockIdx.x;
  const int swz = (lin & 7) * cpx + (lin >> 3);
  const int bx = swz % NBX, by = swz / NBX;
  const int tid = threadIdx.x, lane = tid & 63, w = tid >> 6;
  const int rowBase = by * 128, colBase = bx * 128;
  f32x4 acc[4][4] = {};
  const int srow = tid >> 2, sk = (tid & 3) << 3;
  const short* Ag = A  + (size_t)(rowBase + srow) * Kn + sk;
  const short* Bg = Bt + (size_t)(colBase + srow) * Kn + sk;
  short* AsW = S + w * 512;
  short* BsW = S + 4096 + w * 512;
  const int ar = (w >> 1) * 64, bc = (w & 1) * 64;
  const int lg = lane >> 4, lg8 = lg * 8, lr = lane & 15;

  for (int kt = 0; kt < Kn; kt += 32) {
    __syncthreads();
    gload16(Ag + kt,            AsW);
    gload16(Ag + kt + 64 * Kn,  AsW + 2048);
    gload16(Bg + kt,            BsW);
    gload16(Bg + kt + 64 * Kn,  BsW + 2048);
    __syncthreads();
    short8 af[4], bfr[4];
#pragma unroll
    for (int m = 0; m < 4; ++m) af[m]  = *(const short8*)&S[(ar + m*16 + lr)*32 + lg8];
#pragma unroll
    for (int n = 0; n < 4; ++n) bfr[n] = *(const short8*)&S[4096 + (bc + n*16 + lr)*32 + lg8];
#pragma unroll
    for (int m = 0; m < 4; ++m)
#pragma unroll
      for (int n = 0; n < 4; ++n)
        acc[m][n] = mfma16(af[m], bfr[n], acc[m][n]);
  }

  const int gr0 = rowBase + ar + lg * 4;
  const int gc0 = colBase + bc + lr;

  float bb[4];
#pragma unroll
  for (int n = 0; n < 4; ++n) bb[n] = bias[gc0 + n * 16];
#pragma unroll
  for (int m = 0; m < 4; ++m)
#pragma unroll
    for (int n = 0; n < 4; ++n)
#pragma unroll
      for (int r = 0; r < 4; ++r) acc[m][n][r] += bb[n];

  if (MODE == 0) {
#pragma unroll
    for (int m = 0; m < 4; ++m)
#pragma unroll
      for (int n = 0; n < 4; ++n) {
        const int gc = gc0 + n * 16;
#pragma unroll
        for (int r = 0; r < 4; ++r)
          Cf[(size_t)(gr0 + m*16 + r) * N + gc] = acc[m][n][r];
      }
    return;
  }

  const int which = colBase >> 10;            // block-uniform: 0=q 1=k 2=v
  if (which < 2) {
    const float* gp = (which == 0) ? qg : kg;
    const float* bp = (which == 0) ? qb : kb;
    const float sc = (which == 0) ? 0.1803368801111204f : 1.0f;  // 0.125*log2(e)
    float gam[4], bet[4];
#pragma unroll
    for (int n = 0; n < 4; ++n) { gam[n] = gp[n * 16 + lr]; bet[n] = bp[n * 16 + lr]; }
#pragma unroll
    for (int m = 0; m < 4; ++m)
#pragma unroll
      for (int r = 0; r < 4; ++r) {
        float s1 = 0.f, s2 = 0.f;
#pragma unroll
        for (int n = 0; n < 4; ++n) {
          const float v = acc[m][n][r];
          s1 += v; s2 += v * v;
        }
#pragma unroll
        for (int off = 1; off < 16; off <<= 1) {
          s1 += __shfl_xor(s1, off);
          s2 += __shfl_xor(s2, off);
        }
        const float mu = s1 * 0.015625f;
        const float rs = rsqrtf(s2 * 0.015625f - mu * mu + 1e-5f);
#pragma unroll
        for (int n = 0; n < 4; ++n)
          acc[m][n][r] = ((acc[m][n][r] - mu) * rs * gam[n] + bet[n]) * sc;
      }
  }

  __syncthreads();
  short* Sw = S + w * 2048;
  const int t0 = (rowBase & 2047) + ar;
  const int bidx = (rowBase + ar) >> 11;
  const int hh = ((colBase + bc) & 1023) >> 6;
  const int bh = bidx * Hn + hh;
  const int l8 = lane & 7, ld8 = lane >> 3;

  if (which < 2) {
    short* dst0 = (which == 0) ? qo : ko2;
#pragma unroll
    for (int p = 0; p < 2; ++p) {
#pragma unroll
      for (int mm = 0; mm < 2; ++mm) {
        const int m = p * 2 + mm;
#pragma unroll
        for (int n = 0; n < 4; ++n)
#pragma unroll
          for (int r = 0; r < 4; ++r) {
            const int tl = mm*16 + lg*4 + r;
            const int dl = n*16 + lr;
            Sw[tl*64 + (dl ^ ((tl & 7) << 3))] = f2b(acc[m][n][r]);
          }
      }
#pragma unroll
      for (int i = 0; i < 4; ++i) {
        const int tl = i*8 + ld8;
        short8 v = *(const short8*)&Sw[tl*64 + ((l8*8) ^ ((tl & 7) << 3))];
        const int t = t0 + p*32 + tl;
        *(short8*)&dst0[((size_t)bh * Tn + t) * Dh + l8*8] = v;
      }
    }
  } else {
#pragma unroll
    for (int p = 0; p < 2; ++p) {
#pragma unroll
      for (int nn = 0; nn < 2; ++nn) {
        const int n = p * 2 + nn;
#pragma unroll
        for (int m = 0; m < 4; ++m)
#pragma unroll
          for (int r = 0; r < 4; ++r) {
            const int dl = nn*16 + lr;
            const int tc = m*16 + lg*4 + r;
            Sw[dl*64 + (tc ^ ((dl & 7) << 3))] = f2b(acc[m][n][r]);
          }
      }
#pragma unroll
      for (int i = 0; i < 4; ++i) {
        const int dl = i*8 + ld8;
        short8 v = *(const short8*)&Sw[dl*64 + ((l8*8) ^ ((dl & 7) << 3))];
        const int d = p*32 + dl;
        *(short8*)&vo[((size_t)bh * Dh + d) * Tn + t0 + l8*8] = v;
      }
    }
  }
}

// ---------------- Flash attention: swapped 32x32 (R14/R15-verified numerics) ----------------
// Round-16 change: exchange in PACKED u32 domain — per fragment: 4 v_perm
// packs (bit-identical to the shift/and/or truncation), select-then-shfl the
// 2 words the partner needs, word-level cndmask assembly. 16 perm + 8 shfl +
// 24 cndmask per tile vs R15's ~96 ops. Word table (verified against the
// R14-proven element table case-by-case):
//   hi=0: w0=A0, w1=A1, w2=recv(partner A0), w3=recv(partner A1)
//   hi=1: w0=recv(partner B0), w1=recv(partner B1), w2=B0, w3=B1
// where A0=pack(p[rb],p[rb+1]), A1=pack(p[rb+2],p[rb+3]),
//       B0=pack(p[rb+4],p[rb+5]), B1=pack(p[rb+6],p[rb+7]);
// send = hi ? (A0,A1) : (B0,B1).
__global__ __launch_bounds__(256) void flash32_kernel(
    const short* __restrict__ qp, const short* __restrict__ kp,
    const short* __restrict__ vt, short* __restrict__ y) {
  __shared__ char lds[32768];          // K dbuf 2x8KB | Vt dbuf 2x8KB
  char* ldsK = lds;
  char* ldsV = lds + 16384;

  const int tid = threadIdx.x, l = tid & 63, w = tid >> 6;
  const int l31 = l & 31, hi = l >> 5;

  // XCD swizzle (bijective over 1024 = 8 xcd x 8 bh x 16 qt)
  const int j0 = blockIdx.x;
  const int xcd = j0 & 7, kk0 = j0 >> 3;
  const int bh = 8 * xcd + (kk0 & 7), qt = kk0 >> 3;

  const int qrow0 = qt * 128 + w * 32;
  const short* qrow = qp + ((size_t)bh * Tn + qrow0 + l31) * Dh;
  short8 qf[4];
#pragma unroll
  for (int c = 0; c < 4; ++c)
    qf[c] = *(const short8*)&qrow[c * 16 + hi * 8];

  f32x16 o[2] = {};
  float m = -1e30f, lsum = 0.f;

  const char* kb2 = (const char*)(kp + (size_t)bh * Tn * Dh);
  const char* vb2 = (const char*)(vt + (size_t)bh * Dh * Tn);
  const int sr0 = tid >> 3;            // 0..31 (row within 32-row half)
  const int swzst = (((sr0 & 7) ^ ((sr0 >> 3) << 1)) << 4);
  const int colb = (tid & 7) << 4;
  const int swzrd = (((l31 & 7) ^ ((l31 >> 3) << 1)) << 4);

#define STAGE(jt, bsel)                                                          \
  {                                                                              \
    _Pragma("unroll")                                                            \
    for (int i = 0; i < 2; ++i) {                                                \
      const int row = i * 32 + sr0;                                              \
      const int sw = colb ^ swzst;                                               \
      gload16(kb2 + (size_t)((jt) * 64 + row) * 128 + sw,                        \
              ldsK + (bsel) * 8192 + i * 4096 + tid * 16);                       \
      gload16(vb2 + (size_t)row * (Tn * 2) + (size_t)(jt) * 128 + sw,            \
              ldsV + (bsel) * 8192 + i * 4096 + tid * 16);                       \
    }                                                                            \
  }

  STAGE(0, 0);
  __syncthreads();

  for (int j = 0; j < Tn / 64; ++j) {
    const int cur = j & 1;
    if (j + 1 < Tn / 64) STAGE(j + 1, cur ^ 1);

    const char* Kb = ldsK + cur * 8192;
    const char* Vb = ldsV + cur * 8192;

    // S^T = K * Q^T
    f32x16 p[2] = {};
    __builtin_amdgcn_s_setprio(1);
#pragma unroll
    for (int t = 0; t < 2; ++t) {
      const int row = t * 32 + l31;
#pragma unroll
      for (int c = 0; c < 4; ++c) {
        short8 a = *(const short8*)(Kb + row * 128 + ((c * 32 + hi * 16) ^ swzrd));
        p[t] = mfma32(a, qf[c], p[t]);
      }
    }
    __builtin_amdgcn_s_setprio(0);

    // lane-local online softmax (exp2 domain; scale folded in GEMM1-LN)
    float mx = fmaxf(vmax16(p[0]), vmax16(p[1]));
    mx = fmaxf(mx, __shfl_xor(mx, 32));
    if (!__all(mx - m <= 11.0f)) {
      const float mn = fmaxf(m, mx);
      const float corr = __builtin_amdgcn_exp2f(m - mn);
      lsum *= corr;
      o[0] *= corr;
      o[1] *= corr;
      m = mn;
    }
#pragma unroll
    for (int t = 0; t < 2; ++t)
#pragma unroll
      for (int e = 0; e < 16; ++e)
        p[t][e] = __builtin_amdgcn_exp2f(p[t][e] - m);
    {
      float ps = vsum16(p[0]) + vsum16(p[1]);
      lsum += ps + __shfl_xor(ps, 32);
    }

    // packed exchange (bit-identical to R15): 16 perm + 8 shfl + 24 cndmask
    short8 pf[4];
#pragma unroll
    for (int t = 0; t < 2; ++t)
#pragma unroll
      for (int f = 0; f < 2; ++f) {
        const int rb = 8 * f;
        const unsigned A0 = packtrunc(p[t][rb + 0], p[t][rb + 1]);
        const unsigned A1 = packtrunc(p[t][rb + 2], p[t][rb + 3]);
        const unsigned B0 = packtrunc(p[t][rb + 4], p[t][rb + 5]);
        const unsigned B1 = packtrunc(p[t][rb + 6], p[t][rb + 7]);
        const unsigned S0 = hi ? A0 : B0;
        const unsigned S1 = hi ? A1 : B1;
        const unsigned R0 = (unsigned)__shfl_xor((int)S0, 32);
        const unsigned R1 = (unsigned)__shfl_xor((int)S1, 32);
        i32x4 wv;
        wv[0] = (int)(hi ? R0 : A0);
        wv[1] = (int)(hi ? R1 : A1);
        wv[2] = (int)(hi ? B0 : R0);
        wv[3] = (int)(hi ? B1 : R1);
        pf[2*t + f] = __builtin_bit_cast(short8, wv);
      }

    // O^T += V^T * P^T
    __builtin_amdgcn_s_setprio(1);
#pragma unroll
    for (int dt = 0; dt < 2; ++dt) {
      const int row = dt * 32 + l31;
#pragma unroll
      for (int c = 0; c < 4; ++c) {
        short8 a = *(const short8*)(Vb + row * 128 + ((c * 32 + hi * 16) ^ swzrd));
        o[dt] = mfma32(a, pf[c], o[dt]);
      }
    }
    __builtin_amdgcn_s_setprio(0);

    __syncthreads();
  }
#undef STAGE

  // epilogue: lane-local normalize, direct 8B stores
  const float rl = 1.0f / lsum;
  const int b = bh >> 4, hh = bh & 15;
  const int t = qrow0 + l31;
  short* yrow = y + ((size_t)(b * Tn + t)) * En + hh * 64;
#pragma unroll
  for (int dt = 0; dt < 2; ++dt)
#pragma unroll
    for (int g = 0; g < 4; ++g) {
      short4v v4;
#pragma unroll
      for (int i = 0; i < 4; ++i) v4[i] = f2b(o[dt][g*4 + i] * rl);
      *(short4v*)&yrow[dt*32 + g*8 + hi*4] = v4;
    }
}

extern "C" void kernel_launch(void* const* d_in, const int* in_sizes, int n_in,
                              void* d_out, int out_size, void* d_ws, size_t ws_size,
                              hipStream_t stream) {
  const float* x     = (const float*)d_in[0];
  const float* Wqkv  = (const float*)d_in[1];
  const float* bqkv  = (const float*)d_in[2];
  const float* qg    = (const float*)d_in[3];
  const float* qb    = (const float*)d_in[4];
  const float* kg    = (const float*)d_in[5];
  const float* kb    = (const float*)d_in[6];
  const float* Wproj = (const float*)d_in[7];
  const float* bproj = (const float*)d_in[8];
  float* out = (float*)d_out;

  char* p = (char*)d_ws;
  short* xb     = (short*)p; p += (size_t)Mn * Kn * 2;
  short* wqkvT  = (short*)p; p += (size_t)N1 * Kn * 2;
  short* wprojT = (short*)p; p += (size_t)En * Kn * 2;
  short* qp     = (short*)p; p += (size_t)Mn * Kn * 2;
  short* kp     = (short*)p; p += (size_t)Mn * Kn * 2;
  short* vtb    = (short*)p; p += (size_t)Mn * Kn * 2;
  short* yb     = (short*)p; p += (size_t)Mn * Kn * 2;

  prep_kernel<<<8192, 256, 0, stream>>>(x, xb, Wqkv, wqkvT, Wproj, wprojT);
  gemm_kernel<1><<<(N1 / 128) * (Mn / 128), 256, 0, stream>>>(
      xb, wqkvT, bqkv, nullptr, qp, kp, vtb, qg, qb, kg, kb,
      N1, N1 / 128, (N1 / 128) * (Mn / 128) / 8);
  flash32_kernel<<<1024, 256, 0, stream>>>(qp, kp, vtb, yb);
  gemm_kernel<0><<<(En / 128) * (Mn / 128), 256, 0, stream>>>(
      yb, wprojT, bproj, out, nullptr, nullptr, nullptr, nullptr, nullptr, nullptr, nullptr,
      En, En / 128, (En / 128) * (Mn / 128) / 8);
}

// Round 17
// 236.459 us; speedup vs baseline: 1.0878x; 1.0155x over previous
//
#include <hip/hip_runtime.h>

// Problem constants
#define Hn  16
#define Dh  64
#define Bb  4
#define Tn  2048
#define En  1024
#define Mn  8192           // B*T
#define N1  3072           // 3*E
#define Kn  1024           // E

typedef __attribute__((ext_vector_type(8)))  short  short8;
typedef __attribute__((ext_vector_type(4)))  short  short4v;
typedef __attribute__((ext_vector_type(4)))  float  f32x4;
typedef __attribute__((ext_vector_type(16))) float  f32x16;
typedef __attribute__((ext_vector_type(8)))  __bf16 bf16x8;
typedef __attribute__((ext_vector_type(4)))  int    i32x4;

__device__ __forceinline__ float b2f(short s) {
  unsigned u = ((unsigned)(unsigned short)s) << 16;
  return __builtin_bit_cast(float, u);
}
__device__ __forceinline__ short f2b(float f) {
  unsigned u = __builtin_bit_cast(unsigned, f);
  u += 0x7fffu + ((u >> 16) & 1u);
  return (short)(u >> 16);
}
__device__ __forceinline__ f32x4 mfma16(short8 a, short8 b, f32x4 c) {
  return __builtin_amdgcn_mfma_f32_16x16x32_bf16(
      __builtin_bit_cast(bf16x8, a), __builtin_bit_cast(bf16x8, b), c, 0, 0, 0);
}
__device__ __forceinline__ f32x16 mfma32(short8 a, short8 b, f32x16 c) {
  return __builtin_amdgcn_mfma_f32_32x32x16_bf16(
      __builtin_bit_cast(bf16x8, a), __builtin_bit_cast(bf16x8, b), c, 0, 0, 0);
}
__device__ __forceinline__ void gload16(const void* g, void* l) {
  __builtin_amdgcn_global_load_lds(
      (const __attribute__((address_space(1))) unsigned int*)g,
      (__attribute__((address_space(3))) unsigned int*)l, 16, 0, 0);
}
// pack two f32 into (hi16(b)<<16 | hi16(a)) with one v_perm_b32
__device__ __forceinline__ unsigned packtrunc(float a, float b) {
  return __builtin_amdgcn_perm(__builtin_bit_cast(unsigned, b),
                               __builtin_bit_cast(unsigned, a), 0x07060302u);
}
// max tree as nested triples -> v_max3_f32 fusion; bit-exact (max associative)
__device__ __forceinline__ float vmax16(f32x16 v) {
  float a0 = fmaxf(fmaxf(v[0],  v[1]),  v[2]);
  float a1 = fmaxf(fmaxf(v[3],  v[4]),  v[5]);
  float a2 = fmaxf(fmaxf(v[6],  v[7]),  v[8]);
  float a3 = fmaxf(fmaxf(v[9],  v[10]), v[11]);
  float a4 = fmaxf(fmaxf(v[12], v[13]), v[14]);
  float b0 = fmaxf(fmaxf(a0, a1), a2);
  float b1 = fmaxf(fmaxf(a3, a4), v[15]);
  return fmaxf(b0, b1);
}
__device__ __forceinline__ float vsum16(f32x16 v) {
  float a0 = v[0]+v[1], a1 = v[2]+v[3], a2 = v[4]+v[5], a3 = v[6]+v[7];
  float a4 = v[8]+v[9], a5 = v[10]+v[11], a6 = v[12]+v[13], a7 = v[14]+v[15];
  return ((a0+a1)+(a2+a3)) + ((a4+a5)+(a6+a7));
}

// ---------------- merged preprocessing: cvt_x + transpose both W ----------------
__global__ __launch_bounds__(256) void prep_kernel(
    const float* __restrict__ x, short* __restrict__ xb,
    const float* __restrict__ Wqkv, short* __restrict__ wqkvT,
    const float* __restrict__ Wproj, short* __restrict__ wprojT) {
  __shared__ float tile[32][33];
  const int bid = blockIdx.x, tid = threadIdx.x;
  if (bid < 4096) {
    const size_t i = ((size_t)bid * 256 + tid) * 8;
    f32x4 a = *(const f32x4*)&x[i];
    f32x4 b = *(const f32x4*)&x[i + 4];
    short8 o;
    o[0]=f2b(a[0]); o[1]=f2b(a[1]); o[2]=f2b(a[2]); o[3]=f2b(a[3]);
    o[4]=f2b(b[0]); o[5]=f2b(b[1]); o[6]=f2b(b[2]); o[7]=f2b(b[3]);
    *(short8*)&xb[i] = o;
    return;
  }
  const float* in; short* out; int R, C, bx, by;
  if (bid < 4096 + 3072) {
    const int b2 = bid - 4096;
    in = Wqkv; out = wqkvT; R = Kn; C = N1; bx = b2 % 96; by = b2 / 96;
  } else {
    const int b3 = bid - 7168;
    in = Wproj; out = wprojT; R = Kn; C = En; bx = b3 % 32; by = b3 / 32;
  }
  const int c0 = bx * 32, r0 = by * 32;
  const int lr = tid >> 3, lc = (tid & 7) * 4;
  f32x4 v = *(const f32x4*)&in[(size_t)(r0 + lr) * C + c0 + lc];
  tile[lr][lc] = v[0]; tile[lr][lc+1] = v[1]; tile[lr][lc+2] = v[2]; tile[lr][lc+3] = v[3];
  __syncthreads();
  const int oc = tid >> 3, orr = (tid & 7) * 4;
  short4v ov;
  ov[0] = f2b(tile[orr][oc]);   ov[1] = f2b(tile[orr+1][oc]);
  ov[2] = f2b(tile[orr+2][oc]); ov[3] = f2b(tile[orr+3][oc]);
  *(short4v*)&out[(size_t)(c0 + oc) * R + r0 + orr] = ov;
}

// ---------------- GEMM1 (round-13 proven: fused LN + coalesced epilogue) ----------------
__global__ __launch_bounds__(256) void gemm1_kernel(
    const short* __restrict__ A, const short* __restrict__ Bt,
    const float* __restrict__ bias,
    short* __restrict__ qo, short* __restrict__ ko2, short* __restrict__ vo,
    const float* __restrict__ qg, const float* __restrict__ qb,
    const float* __restrict__ kg, const float* __restrict__ kb,
    int NBX, int cpx) {
  __shared__ short S[8192];
  const int lin = blockIdx.x;
  const int swz = (lin & 7) * cpx + (lin >> 3);
  const int bx = swz % NBX, by = swz / NBX;
  const int tid = threadIdx.x, lane = tid & 63, w = tid >> 6;
  const int rowBase = by * 128, colBase = bx * 128;
  f32x4 acc[4][4] = {};
  const int srow = tid >> 2, sk = (tid & 3) << 3;
  const short* Ag = A  + (size_t)(rowBase + srow) * Kn + sk;
  const short* Bg = Bt + (size_t)(colBase + srow) * Kn + sk;
  short* AsW = S + w * 512;
  short* BsW = S + 4096 + w * 512;
  const int ar = (w >> 1) * 64, bc = (w & 1) * 64;
  const int lg = lane >> 4, lg8 = lg * 8, lr = lane & 15;

  for (int kt = 0; kt < Kn; kt += 32) {
    __syncthreads();
    gload16(Ag + kt,            AsW);
    gload16(Ag + kt + 64 * Kn,  AsW + 2048);
    gload16(Bg + kt,            BsW);
    gload16(Bg + kt + 64 * Kn,  BsW + 2048);
    __syncthreads();
    short8 af[4], bfr[4];
#pragma unroll
    for (int m = 0; m < 4; ++m) af[m]  = *(const short8*)&S[(ar + m*16 + lr)*32 + lg8];
#pragma unroll
    for (int n = 0; n < 4; ++n) bfr[n] = *(const short8*)&S[4096 + (bc + n*16 + lr)*32 + lg8];
#pragma unroll
    for (int m = 0; m < 4; ++m)
#pragma unroll
      for (int n = 0; n < 4; ++n)
        acc[m][n] = mfma16(af[m], bfr[n], acc[m][n]);
  }

  const int gr0 = rowBase + ar + lg * 4;
  const int gc0 = colBase + bc + lr;

  float bb[4];
#pragma unroll
  for (int n = 0; n < 4; ++n) bb[n] = bias[gc0 + n * 16];
#pragma unroll
  for (int m = 0; m < 4; ++m)
#pragma unroll
    for (int n = 0; n < 4; ++n)
#pragma unroll
      for (int r = 0; r < 4; ++r) acc[m][n][r] += bb[n];

  const int which = colBase >> 10;            // block-uniform: 0=q 1=k 2=v
  if (which < 2) {
    const float* gp = (which == 0) ? qg : kg;
    const float* bp = (which == 0) ? qb : kb;
    const float sc = (which == 0) ? 0.1803368801111204f : 1.0f;  // 0.125*log2(e)
    float gam[4], bet[4];
#pragma unroll
    for (int n = 0; n < 4; ++n) { gam[n] = gp[n * 16 + lr]; bet[n] = bp[n * 16 + lr]; }
#pragma unroll
    for (int m = 0; m < 4; ++m)
#pragma unroll
      for (int r = 0; r < 4; ++r) {
        float s1 = 0.f, s2 = 0.f;
#pragma unroll
        for (int n = 0; n < 4; ++n) {
          const float v = acc[m][n][r];
          s1 += v; s2 += v * v;
        }
#pragma unroll
        for (int off = 1; off < 16; off <<= 1) {
          s1 += __shfl_xor(s1, off);
          s2 += __shfl_xor(s2, off);
        }
        const float mu = s1 * 0.015625f;
        const float rs = rsqrtf(s2 * 0.015625f - mu * mu + 1e-5f);
#pragma unroll
        for (int n = 0; n < 4; ++n)
          acc[m][n][r] = ((acc[m][n][r] - mu) * rs * gam[n] + bet[n]) * sc;
      }
  }

  __syncthreads();
  short* Sw = S + w * 2048;
  const int t0 = (rowBase & 2047) + ar;
  const int bidx = (rowBase + ar) >> 11;
  const int hh = ((colBase + bc) & 1023) >> 6;
  const int bh = bidx * Hn + hh;
  const int l8 = lane & 7, ld8 = lane >> 3;

  if (which < 2) {
    short* dst0 = (which == 0) ? qo : ko2;
#pragma unroll
    for (int p = 0; p < 2; ++p) {
#pragma unroll
      for (int mm = 0; mm < 2; ++mm) {
        const int m = p * 2 + mm;
#pragma unroll
        for (int n = 0; n < 4; ++n)
#pragma unroll
          for (int r = 0; r < 4; ++r) {
            const int tl = mm*16 + lg*4 + r;
            const int dl = n*16 + lr;
            Sw[tl*64 + (dl ^ ((tl & 7) << 3))] = f2b(acc[m][n][r]);
          }
      }
#pragma unroll
      for (int i = 0; i < 4; ++i) {
        const int tl = i*8 + ld8;
        short8 v = *(const short8*)&Sw[tl*64 + ((l8*8) ^ ((tl & 7) << 3))];
        const int t = t0 + p*32 + tl;
        *(short8*)&dst0[((size_t)bh * Tn + t) * Dh + l8*8] = v;
      }
    }
  } else {
#pragma unroll
    for (int p = 0; p < 2; ++p) {
#pragma unroll
      for (int nn = 0; nn < 2; ++nn) {
        const int n = p * 2 + nn;
#pragma unroll
        for (int m = 0; m < 4; ++m)
#pragma unroll
          for (int r = 0; r < 4; ++r) {
            const int dl = nn*16 + lr;
            const int tc = m*16 + lg*4 + r;
            Sw[dl*64 + (tc ^ ((dl & 7) << 3))] = f2b(acc[m][n][r]);
          }
      }
#pragma unroll
      for (int i = 0; i < 4; ++i) {
        const int dl = i*8 + ld8;
        short8 v = *(const short8*)&Sw[dl*64 + ((l8*8) ^ ((dl & 7) << 3))];
        const int d = p*32 + dl;
        *(short8*)&vo[((size_t)bh * Dh + d) * Tn + t0 + l8*8] = v;
      }
    }
  }
}

// ---------------- GEMM2: 64x128 tiles (4 blocks/CU) ----------------
// C[M][N] = A[M][K] * Bt[N][K]^T + bias, fp32 out. Same per-wave fragment
// maps as gemm1; wave grid 2x2 over a 64x128 tile -> acc[2][4]. Bit-exact
// same per-element accumulation order as the 128^2 version.
__global__ __launch_bounds__(256) void gemm2_kernel(
    const short* __restrict__ A, const short* __restrict__ Bt,
    const float* __restrict__ bias, float* __restrict__ Cf,
    int N, int NBX, int cpx) {
  __shared__ short S[6144];     // A 64x32 (2048 sh) | B 128x32 (4096 sh)
  const int lin = blockIdx.x;
  const int swz = (lin & 7) * cpx + (lin >> 3);
  const int bx = swz % NBX, by = swz / NBX;
  const int tid = threadIdx.x, lane = tid & 63, w = tid >> 6;
  const int rowBase = by * 64, colBase = bx * 128;
  f32x4 acc[2][4] = {};
  const int srow = tid >> 2, sk = (tid & 3) << 3;
  const short* Ag = A  + (size_t)(rowBase + srow) * Kn + sk;
  const short* Bg = Bt + (size_t)(colBase + srow) * Kn + sk;
  const int ar = (w >> 1) * 32, bc = (w & 1) * 64;
  const int lg = lane >> 4, lg8 = lg * 8, lr = lane & 15;

  for (int kt = 0; kt < Kn; kt += 32) {
    __syncthreads();
    gload16(Ag + kt,            S + w * 512);          // A rows 0..63
    gload16(Bg + kt,            S + 2048 + w * 512);   // B rows 0..63
    gload16(Bg + kt + 64 * Kn,  S + 4096 + w * 512);   // B rows 64..127
    __syncthreads();
    short8 af[2], bfr[4];
#pragma unroll
    for (int m = 0; m < 2; ++m) af[m]  = *(const short8*)&S[(ar + m*16 + lr)*32 + lg8];
#pragma unroll
    for (int n = 0; n < 4; ++n) bfr[n] = *(const short8*)&S[2048 + (bc + n*16 + lr)*32 + lg8];
#pragma unroll
    for (int m = 0; m < 2; ++m)
#pragma unroll
      for (int n = 0; n < 4; ++n)
        acc[m][n] = mfma16(af[m], bfr[n], acc[m][n]);
  }

  const int gr0 = rowBase + ar + lg * 4;
  const int gc0 = colBase + bc + lr;
  float bb[4];
#pragma unroll
  for (int n = 0; n < 4; ++n) bb[n] = bias[gc0 + n * 16];
#pragma unroll
  for (int m = 0; m < 2; ++m)
#pragma unroll
    for (int n = 0; n < 4; ++n) {
      const int gc = gc0 + n * 16;
#pragma unroll
      for (int r = 0; r < 4; ++r)
        Cf[(size_t)(gr0 + m*16 + r) * N + gc] = acc[m][n][r] + bb[n];
    }
}

// ---------------- Flash attention: swapped 32x32 (R16 proven) ----------------
__global__ __launch_bounds__(256) void flash32_kernel(
    const short* __restrict__ qp, const short* __restrict__ kp,
    const short* __restrict__ vt, short* __restrict__ y) {
  __shared__ char lds[32768];          // K dbuf 2x8KB | Vt dbuf 2x8KB
  char* ldsK = lds;
  char* ldsV = lds + 16384;

  const int tid = threadIdx.x, l = tid & 63, w = tid >> 6;
  const int l31 = l & 31, hi = l >> 5;

  // XCD swizzle (bijective over 1024 = 8 xcd x 8 bh x 16 qt)
  const int j0 = blockIdx.x;
  const int xcd = j0 & 7, kk0 = j0 >> 3;
  const int bh = 8 * xcd + (kk0 & 7), qt = kk0 >> 3;

  const int qrow0 = qt * 128 + w * 32;
  const short* qrow = qp + ((size_t)bh * Tn + qrow0 + l31) * Dh;
  short8 qf[4];
#pragma unroll
  for (int c = 0; c < 4; ++c)
    qf[c] = *(const short8*)&qrow[c * 16 + hi * 8];

  f32x16 o[2] = {};
  float m = -1e30f, lsum = 0.f;

  const char* kb2 = (const char*)(kp + (size_t)bh * Tn * Dh);
  const char* vb2 = (const char*)(vt + (size_t)bh * Dh * Tn);
  const int sr0 = tid >> 3;            // 0..31 (row within 32-row half)
  const int swzst = (((sr0 & 7) ^ ((sr0 >> 3) << 1)) << 4);
  const int colb = (tid & 7) << 4;
  const int swzrd = (((l31 & 7) ^ ((l31 >> 3) << 1)) << 4);

#define STAGE(jt, bsel)                                                          \
  {                                                                              \
    _Pragma("unroll")                                                            \
    for (int i = 0; i < 2; ++i) {                                                \
      const int row = i * 32 + sr0;                                              \
      const int sw = colb ^ swzst;                                               \
      gload16(kb2 + (size_t)((jt) * 64 + row) * 128 + sw,                        \
              ldsK + (bsel) * 8192 + i * 4096 + tid * 16);                       \
      gload16(vb2 + (size_t)row * (Tn * 2) + (size_t)(jt) * 128 + sw,            \
              ldsV + (bsel) * 8192 + i * 4096 + tid * 16);                       \
    }                                                                            \
  }

  STAGE(0, 0);
  __syncthreads();

  for (int j = 0; j < Tn / 64; ++j) {
    const int cur = j & 1;
    if (j + 1 < Tn / 64) STAGE(j + 1, cur ^ 1);

    const char* Kb = ldsK + cur * 8192;
    const char* Vb = ldsV + cur * 8192;

    // S^T = K * Q^T
    f32x16 p[2] = {};
    __builtin_amdgcn_s_setprio(1);
#pragma unroll
    for (int t = 0; t < 2; ++t) {
      const int row = t * 32 + l31;
#pragma unroll
      for (int c = 0; c < 4; ++c) {
        short8 a = *(const short8*)(Kb + row * 128 + ((c * 32 + hi * 16) ^ swzrd));
        p[t] = mfma32(a, qf[c], p[t]);
      }
    }
    __builtin_amdgcn_s_setprio(0);

    // lane-local online softmax (exp2 domain; scale folded in GEMM1-LN)
    float mx = fmaxf(vmax16(p[0]), vmax16(p[1]));
    mx = fmaxf(mx, __shfl_xor(mx, 32));
    if (!__all(mx - m <= 11.0f)) {
      const float mn = fmaxf(m, mx);
      const float corr = __builtin_amdgcn_exp2f(m - mn);
      lsum *= corr;
      o[0] *= corr;
      o[1] *= corr;
      m = mn;
    }
#pragma unroll
    for (int t = 0; t < 2; ++t)
#pragma unroll
      for (int e = 0; e < 16; ++e)
        p[t][e] = __builtin_amdgcn_exp2f(p[t][e] - m);
    {
      float ps = vsum16(p[0]) + vsum16(p[1]);
      lsum += ps + __shfl_xor(ps, 32);
    }

    // packed exchange: 16 perm + 8 shfl + 24 cndmask (R16 proven)
    short8 pf[4];
#pragma unroll
    for (int t = 0; t < 2; ++t)
#pragma unroll
      for (int f = 0; f < 2; ++f) {
        const int rb = 8 * f;
        const unsigned A0 = packtrunc(p[t][rb + 0], p[t][rb + 1]);
        const unsigned A1 = packtrunc(p[t][rb + 2], p[t][rb + 3]);
        const unsigned B0 = packtrunc(p[t][rb + 4], p[t][rb + 5]);
        const unsigned B1 = packtrunc(p[t][rb + 6], p[t][rb + 7]);
        const unsigned S0 = hi ? A0 : B0;
        const unsigned S1 = hi ? A1 : B1;
        const unsigned R0 = (unsigned)__shfl_xor((int)S0, 32);
        const unsigned R1 = (unsigned)__shfl_xor((int)S1, 32);
        i32x4 wv;
        wv[0] = (int)(hi ? R0 : A0);
        wv[1] = (int)(hi ? R1 : A1);
        wv[2] = (int)(hi ? B0 : R0);
        wv[3] = (int)(hi ? B1 : R1);
        pf[2*t + f] = __builtin_bit_cast(short8, wv);
      }

    // O^T += V^T * P^T
    __builtin_amdgcn_s_setprio(1);
#pragma unroll
    for (int dt = 0; dt < 2; ++dt) {
      const int row = dt * 32 + l31;
#pragma unroll
      for (int c = 0; c < 4; ++c) {
        short8 a = *(const short8*)(Vb + row * 128 + ((c * 32 + hi * 16) ^ swzrd));
        o[dt] = mfma32(a, pf[c], o[dt]);
      }
    }
    __builtin_amdgcn_s_setprio(0);

    __syncthreads();
  }
#undef STAGE

  // epilogue: lane-local normalize, direct 8B stores
  const float rl = 1.0f / lsum;
  const int b = bh >> 4, hh = bh & 15;
  const int t = qrow0 + l31;
  short* yrow = y + ((size_t)(b * Tn + t)) * En + hh * 64;
#pragma unroll
  for (int dt = 0; dt < 2; ++dt)
#pragma unroll
    for (int g = 0; g < 4; ++g) {
      short4v v4;
#pragma unroll
      for (int i = 0; i < 4; ++i) v4[i] = f2b(o[dt][g*4 + i] * rl);
      *(short4v*)&yrow[dt*32 + g*8 + hi*4] = v4;
    }
}

extern "C" void kernel_launch(void* const* d_in, const int* in_sizes, int n_in,
                              void* d_out, int out_size, void* d_ws, size_t ws_size,
                              hipStream_t stream) {
  const float* x     = (const float*)d_in[0];
  const float* Wqkv  = (const float*)d_in[1];
  const float* bqkv  = (const float*)d_in[2];
  const float* qg    = (const float*)d_in[3];
  const float* qb    = (const float*)d_in[4];
  const float* kg    = (const float*)d_in[5];
  const float* kb    = (const float*)d_in[6];
  const float* Wproj = (const float*)d_in[7];
  const float* bproj = (const float*)d_in[8];
  float* out = (float*)d_out;

  char* p = (char*)d_ws;
  short* xb     = (short*)p; p += (size_t)Mn * Kn * 2;
  short* wqkvT  = (short*)p; p += (size_t)N1 * Kn * 2;
  short* wprojT = (short*)p; p += (size_t)En * Kn * 2;
  short* qp     = (short*)p; p += (size_t)Mn * Kn * 2;
  short* kp     = (short*)p; p += (size_t)Mn * Kn * 2;
  short* vtb    = (short*)p; p += (size_t)Mn * Kn * 2;
  short* yb     = (short*)p; p += (size_t)Mn * Kn * 2;

  prep_kernel<<<8192, 256, 0, stream>>>(x, xb, Wqkv, wqkvT, Wproj, wprojT);
  gemm1_kernel<<<(N1 / 128) * (Mn / 128), 256, 0, stream>>>(
      xb, wqkvT, bqkv, qp, kp, vtb, qg, qb, kg, kb,
      N1 / 128, (N1 / 128) * (Mn / 128) / 8);
  flash32_kernel<<<1024, 256, 0, stream>>>(qp, kp, vtb, yb);
  // GEMM2: 64x128 tiles -> 8 x 128 = 1024 blocks (4/CU)
  gemm2_kernel<<<(En / 128) * (Mn / 64), 256, 0, stream>>>(
      yb, wprojT, bproj, out, En, En / 128, (En / 128) * (Mn / 64) / 8);
}